// Round 1
// baseline (1046.154 us; speedup 1.0000x reference)
//
#include <hip/hip_runtime.h>
#include <hip/hip_bf16.h>
#include <stdint.h>

// Problem constants (QuantizedLinear_29463475650732): B=4, S=2048, IN=4096, OUT=11008
#define M_DIM 8192   // B*S
#define N_DIM 11008  // OUT
#define K_DIM 4096   // IN
#define NGROUP 32    // K_DIM/128

#define BM 128
#define BN 128
#define BK 64

typedef __attribute__((ext_vector_type(4))) float f32x4;
typedef __attribute__((ext_vector_type(8))) short short8;
typedef __attribute__((ext_vector_type(8))) __bf16 bf16x8;

static_assert(M_DIM % BM == 0 && N_DIM % BN == 0 && K_DIM % BK == 0, "tiling");

__device__ __forceinline__ unsigned short f2bf(float f) {
  union { float f; unsigned int u; } v; v.f = f;
  unsigned int r = v.u + 0x7FFFu + ((v.u >> 16) & 1u);  // RNE, no NaN inputs here
  return (unsigned short)(r >> 16);
}

// ---------- prepass 1: x fp32 -> bf16 ----------
__global__ __launch_bounds__(256) void cvt_x_kernel(const float* __restrict__ x,
                                                    unsigned short* __restrict__ xb) {
  size_t i = ((size_t)blockIdx.x * 256 + threadIdx.x) * 8;
  float4 a = *(const float4*)(x + i);
  float4 b = *(const float4*)(x + i + 4);
  short8 o;
  o[0] = (short)f2bf(a.x); o[1] = (short)f2bf(a.y);
  o[2] = (short)f2bf(a.z); o[3] = (short)f2bf(a.w);
  o[4] = (short)f2bf(b.x); o[5] = (short)f2bf(b.y);
  o[6] = (short)f2bf(b.z); o[7] = (short)f2bf(b.w);
  *(short8*)(xb + i) = o;
}

// ---------- prepass 2: dequant packed int4 -> bf16 W[N][K] ----------
__global__ __launch_bounds__(256) void dequant_kernel(const int* __restrict__ qw,
                                                      const float* __restrict__ sc,
                                                      const float* __restrict__ zp,
                                                      unsigned short* __restrict__ W) {
  size_t chunk = (size_t)blockIdx.x * 256 + threadIdx.x;  // one chunk = 4 packed int32 = 8 weights
  int row = (int)(chunk >> 9);   // / 512 chunks per row (2048 packed / 4)
  int c4  = (int)(chunk & 511);
  int g   = c4 >> 4;             // k0 = c4*8; group = k0/128 = c4/16 (no straddle)
  float s = sc[row * NGROUP + g];
  float z = zp[row * NGROUP + g];
  int4 q = *(const int4*)(qw + (size_t)row * 2048 + c4 * 4);
  int qq[4] = {q.x, q.y, q.z, q.w};
  short8 o;
#pragma unroll
  for (int t = 0; t < 4; ++t) {
    o[2 * t]     = (short)f2bf(((float)(qq[t] & 15)        - z) * s);
    o[2 * t + 1] = (short)f2bf(((float)((qq[t] >> 4) & 15) - z) * s);
  }
  *(short8*)(W + (size_t)row * K_DIM + (size_t)c4 * 8) = o;
}

// ---------- main GEMM: C[M][N] = A[M][K](bf16) * B[N][K](bf16)^T ----------
__device__ __forceinline__ void gload_lds16(const void* g, void* l) {
  __builtin_amdgcn_global_load_lds((__attribute__((address_space(1))) void*)g,
                                   (__attribute__((address_space(3))) void*)l,
                                   16, 0, 0);
}

__global__ __launch_bounds__(256, 2) void gemm_bt_kernel(const unsigned short* __restrict__ A,
                                                         const unsigned short* __restrict__ B,
                                                         float* __restrict__ C) {
  __shared__ __align__(16) unsigned short As[BM * BK];
  __shared__ __align__(16) unsigned short Bs[BN * BK];

  const int tid  = threadIdx.x;
  const int wave = tid >> 6;
  const int lane = tid & 63;

  const int bn = blockIdx.x;
  const int bm = blockIdx.y;
  const size_t row0 = (size_t)bm * BM;
  const size_t col0 = (size_t)bn * BN;

  // staging geometry: chunk = 1KB = 8 rows x 64 bf16; lane -> (row, col) within chunk
  const int srow = lane >> 3;         // 0..7
  const int scol = (lane & 7) * 8;    // bf16 col, 8 elems = 16B per lane

  // wave -> 64x64 output subtile
  const int wr = wave >> 1;
  const int wc = wave & 1;
  const int fr = lane & 15;           // fragment row (A) / col (B)
  const int kl = (lane >> 4) * 8;     // per-lane k offset within 32

  f32x4 acc[4][4];
#pragma unroll
  for (int i = 0; i < 4; ++i)
#pragma unroll
    for (int j = 0; j < 4; ++j) acc[i][j] = (f32x4){0.f, 0.f, 0.f, 0.f};

  for (int kt = 0; kt < K_DIM / BK; ++kt) {
    const int kbase = kt * BK;
    // stage A and B tiles: 16 chunks each, wave w handles chunks 4w..4w+3
#pragma unroll
    for (int c = 0; c < 4; ++c) {
      const int chunk = wave * 4 + c;
      const unsigned short* ga =
          A + (row0 + (size_t)(chunk * 8 + srow)) * K_DIM + kbase + scol;
      gload_lds16(ga, &As[chunk * 512]);
      const unsigned short* gb =
          B + (col0 + (size_t)(chunk * 8 + srow)) * K_DIM + kbase + scol;
      gload_lds16(gb, &Bs[chunk * 512]);
    }
    __syncthreads();

#pragma unroll
    for (int kk = 0; kk < BK; kk += 32) {
      bf16x8 a[4], b[4];
#pragma unroll
      for (int i = 0; i < 4; ++i)
        a[i] = *(const bf16x8*)&As[(wr * 64 + i * 16 + fr) * BK + kk + kl];
#pragma unroll
      for (int i = 0; i < 4; ++i)
        b[i] = *(const bf16x8*)&Bs[(wc * 64 + i * 16 + fr) * BK + kk + kl];
#pragma unroll
      for (int i = 0; i < 4; ++i)
#pragma unroll
        for (int j = 0; j < 4; ++j)
          acc[i][j] = __builtin_amdgcn_mfma_f32_16x16x32_bf16(a[i], b[j], acc[i][j], 0, 0, 0);
    }
    __syncthreads();
  }

  // epilogue: C/D layout col = lane&15, row = (lane>>4)*4 + v  [m89/m91 verified]
  const int orow = (lane >> 4) * 4;
#pragma unroll
  for (int i = 0; i < 4; ++i) {
#pragma unroll
    for (int j = 0; j < 4; ++j) {
      const size_t r  = row0 + wr * 64 + i * 16 + orow;
      const size_t cc = col0 + wc * 64 + j * 16 + fr;
#pragma unroll
      for (int v = 0; v < 4; ++v)
        C[(r + v) * N_DIM + cc] = acc[i][j][v];
    }
  }
}

// ---------- fallback (only if d_ws too small): naive fused ----------
__global__ __launch_bounds__(256) void fallback_kernel(const float* __restrict__ x,
                                                       const int* __restrict__ qw,
                                                       const float* __restrict__ sc,
                                                       const float* __restrict__ zp,
                                                       float* __restrict__ out) {
  __shared__ float xs[K_DIM];
  const int m = blockIdx.y;
  const int n = blockIdx.x * 256 + threadIdx.x;
  for (int i = threadIdx.x; i < K_DIM; i += 256) xs[i] = x[(size_t)m * K_DIM + i];
  __syncthreads();
  float acc = 0.f;
  const int* wrow = qw + (size_t)n * (K_DIM / 2);
  for (int g = 0; g < NGROUP; ++g) {
    float s = sc[n * NGROUP + g];
    float z = zp[n * NGROUP + g];
    float partial = 0.f;
    for (int p = 0; p < 64; ++p) {
      int q = wrow[g * 64 + p];
      partial += xs[g * 128 + 2 * p]     * ((float)(q & 15) - z);
      partial += xs[g * 128 + 2 * p + 1] * ((float)((q >> 4) & 15) - z);
    }
    acc = fmaf(partial, s, acc);
  }
  out[(size_t)m * N_DIM + n] = acc;
}

extern "C" void kernel_launch(void* const* d_in, const int* in_sizes, int n_in,
                              void* d_out, int out_size, void* d_ws, size_t ws_size,
                              hipStream_t stream) {
  const float* x  = (const float*)d_in[0];
  const int*   qw = (const int*)d_in[1];
  const float* sc = (const float*)d_in[2];
  const float* zp = (const float*)d_in[3];
  float* out = (float*)d_out;

  const size_t xb_bytes = (size_t)M_DIM * K_DIM * 2;  //  67,108,864
  const size_t wb_bytes = (size_t)N_DIM * K_DIM * 2;  //  90,177,536

  if (ws_size >= xb_bytes + wb_bytes) {
    unsigned short* xb = (unsigned short*)d_ws;
    unsigned short* wb = (unsigned short*)((char*)d_ws + xb_bytes);
    // prepass 1: x -> bf16 (33.5M elems, 8/thread)
    cvt_x_kernel<<<dim3((unsigned)((size_t)M_DIM * K_DIM / (256 * 8))), 256, 0, stream>>>(x, xb);
    // prepass 2: dequant W -> bf16 [N][K] (5.6M chunks of 4 int32)
    dequant_kernel<<<dim3((unsigned)((size_t)N_DIM * (K_DIM / 2) / 4 / 256)), 256, 0, stream>>>(qw, sc, zp, wb);
    // GEMM
    dim3 grid(N_DIM / BN, M_DIM / BM);
    gemm_bt_kernel<<<grid, 256, 0, stream>>>(xb, wb, out);
  } else {
    dim3 grid(N_DIM / 256, M_DIM);
    fallback_kernel<<<grid, 256, 0, stream>>>(x, qw, sc, zp, out);
  }
}

// Round 2
// 808.449 us; speedup vs baseline: 1.2940x; 1.2940x over previous
//
#include <hip/hip_runtime.h>
#include <hip/hip_bf16.h>
#include <stdint.h>

// Problem constants: B=4, S=2048, IN=4096, OUT=11008
#define M_DIM 8192   // B*S
#define N_DIM 11008  // OUT
#define K_DIM 4096   // IN
#define NGROUP 32    // K_DIM/128

#define BM 256
#define BN 256
#define BK 64
#define NT (K_DIM / BK)  // 64 K-tiles

typedef __attribute__((ext_vector_type(4))) float f32x4;
typedef __attribute__((ext_vector_type(8))) short short8;
typedef __attribute__((ext_vector_type(8))) __bf16 bf16x8;

static_assert(M_DIM % BM == 0 && N_DIM % BN == 0 && K_DIM % BK == 0, "tiling");

__device__ __forceinline__ unsigned short f2bf(float f) {
  union { float f; unsigned int u; } v; v.f = f;
  unsigned int r = v.u + 0x7FFFu + ((v.u >> 16) & 1u);  // RNE
  return (unsigned short)(r >> 16);
}

// ---------- prepass 1: x fp32 -> bf16 ----------
__global__ __launch_bounds__(256) void cvt_x_kernel(const float* __restrict__ x,
                                                    unsigned short* __restrict__ xb) {
  size_t i = ((size_t)blockIdx.x * 256 + threadIdx.x) * 8;
  float4 a = *(const float4*)(x + i);
  float4 b = *(const float4*)(x + i + 4);
  short8 o;
  o[0] = (short)f2bf(a.x); o[1] = (short)f2bf(a.y);
  o[2] = (short)f2bf(a.z); o[3] = (short)f2bf(a.w);
  o[4] = (short)f2bf(b.x); o[5] = (short)f2bf(b.y);
  o[6] = (short)f2bf(b.z); o[7] = (short)f2bf(b.w);
  *(short8*)(xb + i) = o;
}

// ---------- prepass 2: dequant packed int4 -> bf16 W[N][K] ----------
__global__ __launch_bounds__(256) void dequant_kernel(const int* __restrict__ qw,
                                                      const float* __restrict__ sc,
                                                      const float* __restrict__ zp,
                                                      unsigned short* __restrict__ W) {
  size_t chunk = (size_t)blockIdx.x * 256 + threadIdx.x;  // 4 packed int32 = 8 weights
  int row = (int)(chunk >> 9);
  int c4  = (int)(chunk & 511);
  int g   = c4 >> 4;
  float s = sc[row * NGROUP + g];
  float z = zp[row * NGROUP + g];
  int4 q = *(const int4*)(qw + (size_t)row * 2048 + c4 * 4);
  int qq[4] = {q.x, q.y, q.z, q.w};
  short8 o;
#pragma unroll
  for (int t = 0; t < 4; ++t) {
    o[2 * t]     = (short)f2bf(((float)(qq[t] & 15)        - z) * s);
    o[2 * t + 1] = (short)f2bf(((float)((qq[t] >> 4) & 15) - z) * s);
  }
  *(short8*)(W + (size_t)row * K_DIM + (size_t)c4 * 8) = o;
}

// ---------- 256x256 8-phase GEMM: C[M][N] = A[M][K] * B[N][K]^T (bf16 in, f32 out) ----------
__device__ __forceinline__ void gload_lds16(const void* g, void* l) {
  __builtin_amdgcn_global_load_lds((__attribute__((address_space(1))) void*)g,
                                   (__attribute__((address_space(3))) void*)l,
                                   16, 0, 0);
}

// Stage one k-half panel [256 rows][32 cols] bf16 = 16KB, 2 x global_load_lds per thread.
// LDS dest is LINEAR (wave-uniform base + lane*16); swizzle is applied on the GLOBAL
// source column: physical 16B-block cblk holds logical cblk ^ ((row>>1)&3).
__device__ __forceinline__ void stage_half(unsigned short* panel,
                                           const unsigned short* gbase,  // matrix base + tile_row0*K
                                           int kt, int kh, int tid, int wave) {
  const int cl = (tid & 3) ^ ((tid >> 3) & 3);  // logical 16B-block for this lane's physical slot
  const int r0 = tid >> 2;                      // 0..127
  const int colg = kt * 64 + kh * 32 + cl * 8;  // global column (bf16 elems)
#pragma unroll
  for (int i = 0; i < 2; ++i) {
    const unsigned short* src = gbase + (size_t)(i * 128 + r0) * K_DIM + colg;
    unsigned short* dst = panel + (size_t)(i * 512 + wave * 64) * 8;  // wave-uniform + lane*16B
    gload_lds16(src, dst);
  }
}

#define VMC(N) asm volatile("s_waitcnt vmcnt(" #N ")" ::: "memory")

// One phase: 8 ds_read_b128 + optional half-tile prefetch + barrier + 16 MFMA + barrier.
#define PHASE(PA, PB, MH, STAGE_STMT, VM_STMT)                                      \
  {                                                                                 \
    bf16x8 av[4], bv[4];                                                            \
    _Pragma("unroll") for (int m_ = 0; m_ < 4; ++m_)                                \
      av[m_] = *(const bf16x8*)&(PA)[abase + ((MH)*4 + m_) * 512];                  \
    _Pragma("unroll") for (int n_ = 0; n_ < 4; ++n_)                                \
      bv[n_] = *(const bf16x8*)&(PB)[bbase + n_ * 512];                             \
    STAGE_STMT;                                                                     \
    __builtin_amdgcn_s_barrier();                                                   \
    __builtin_amdgcn_s_setprio(1);                                                  \
    _Pragma("unroll") for (int m_ = 0; m_ < 4; ++m_)                                \
      _Pragma("unroll") for (int n_ = 0; n_ < 4; ++n_)                              \
        acc[(MH)*4 + m_][n_] =                                                      \
            __builtin_amdgcn_mfma_f32_16x16x32_bf16(av[m_], bv[n_],                 \
                                                    acc[(MH)*4 + m_][n_], 0, 0, 0); \
    __builtin_amdgcn_s_setprio(0);                                                  \
    VM_STMT;                                                                        \
    __builtin_amdgcn_s_barrier();                                                   \
  }

__global__ __launch_bounds__(512, 2) void gemm_8phase_kernel(const unsigned short* __restrict__ A,
                                                             const unsigned short* __restrict__ B,
                                                             float* __restrict__ C) {
  extern __shared__ unsigned short lds[];
  unsigned short* As = lds;            // [2 buf][2 kh][256*32]  = 64KB
  unsigned short* Bs = lds + 32768;    // same                   = 64KB

  const int tid  = threadIdx.x;
  const int wave = tid >> 6;
  const int lane = tid & 63;
  const int wm = wave >> 2;   // 0..1 -> 128-row slab
  const int wn = wave & 3;    // 0..3 -> 64-col slab
  const int fr = lane & 15;
  const int cp = (lane >> 4) ^ ((fr >> 1) & 3);  // swizzled physical 16B-block

  // XCD-chunked block swizzle (1376 = 8*172, bijective), then bm-major mapping
  const int wg  = blockIdx.x;
  const int swz = (wg & 7) * 172 + (wg >> 3);
  const int bm = swz / 43;
  const int bn = swz % 43;
  const size_t row0 = (size_t)bm * BM;
  const size_t col0 = (size_t)bn * BN;

  const unsigned short* Ab = A + row0 * K_DIM;
  const unsigned short* Bb = B + col0 * K_DIM;

  // fragment LDS element offsets (panel-local); frag (mi): abase + mi*512
  const int abase = (wm * 128 + fr) * 32 + cp * 8;
  const int bbase = (wn * 64 + fr) * 32 + cp * 8;

  f32x4 acc[8][4];
#pragma unroll
  for (int i = 0; i < 8; ++i)
#pragma unroll
    for (int j = 0; j < 4; ++j) acc[i][j] = (f32x4){0.f, 0.f, 0.f, 0.f};

  // ---- prologue: stage tile 0 fully (Ak0, Bk0, Ak1, Bk1) ----
  stage_half(As + 0 * 8192, Ab, 0, 0, tid, wave);
  stage_half(Bs + 0 * 8192, Bb, 0, 0, tid, wave);
  stage_half(As + 1 * 8192, Ab, 0, 1, tid, wave);
  stage_half(Bs + 1 * 8192, Bb, 0, 1, tid, wave);
  VMC(4);                       // Ak0,Bk0 landed; Ak1,Bk1 may be in flight
  __builtin_amdgcn_s_barrier();

  // ---- main loop: 4 phases per K-tile, 1 half-tile prefetch per phase ----
  for (int T = 0; T < NT - 1; ++T) {
    const int buf = T & 1, nb = buf ^ 1;
    unsigned short* A0 = As + (buf * 2 + 0) * 8192;
    unsigned short* A1 = As + (buf * 2 + 1) * 8192;
    unsigned short* B0 = Bs + (buf * 2 + 0) * 8192;
    unsigned short* B1 = Bs + (buf * 2 + 1) * 8192;
    unsigned short* nA0 = As + (nb * 2 + 0) * 8192;
    unsigned short* nA1 = As + (nb * 2 + 1) * 8192;
    unsigned short* nB0 = Bs + (nb * 2 + 0) * 8192;
    unsigned short* nB1 = Bs + (nb * 2 + 1) * 8192;

    // ph1: compute (k0, m-half0), prefetch (T+1).Ak0  [slot dead since T-1]
    PHASE(A0, B0, 0, stage_half(nA0, Ab, T + 1, 0, tid, wave), );
    // ph2: compute (k0, m-half1), prefetch (T+1).Bk0; wait T.Ak1,T.Bk1 (for ph3)
    PHASE(A0, B0, 1, stage_half(nB0, Bb, T + 1, 0, tid, wave), VMC(4));
    // ph3: compute (k1, m-half0), prefetch (T+1).Ak1
    PHASE(A1, B1, 0, stage_half(nA1, Ab, T + 1, 1, tid, wave), );
    // ph4: compute (k1, m-half1), prefetch (T+1).Bk1; wait (T+1).Ak0,Bk0 (for next ph1)
    PHASE(A1, B1, 1, stage_half(nB1, Bb, T + 1, 1, tid, wave), VMC(4));
  }
  // ---- last tile: no prefetch; drain before k1 phases ----
  {
    const int buf = (NT - 1) & 1;
    unsigned short* A0 = As + (buf * 2 + 0) * 8192;
    unsigned short* A1 = As + (buf * 2 + 1) * 8192;
    unsigned short* B0 = Bs + (buf * 2 + 0) * 8192;
    unsigned short* B1 = Bs + (buf * 2 + 1) * 8192;
    PHASE(A0, B0, 0, , );
    PHASE(A0, B0, 1, , VMC(0));
    PHASE(A1, B1, 0, , );
    PHASE(A1, B1, 1, , );
  }

  // ---- epilogue: C/D layout col = lane&15, row = (lane>>4)*4 + v ----
  const int orow = (lane >> 4) * 4;
#pragma unroll
  for (int mi = 0; mi < 8; ++mi) {
#pragma unroll
    for (int n = 0; n < 4; ++n) {
      const size_t r = row0 + wm * 128 + mi * 16 + orow;
      const size_t c = col0 + wn * 64 + n * 16 + fr;
#pragma unroll
      for (int v = 0; v < 4; ++v)
        C[(r + v) * N_DIM + c] = acc[mi][n][v];
    }
  }
}

// ---------- fallback (only if d_ws too small): naive fused ----------
__global__ __launch_bounds__(256) void fallback_kernel(const float* __restrict__ x,
                                                       const int* __restrict__ qw,
                                                       const float* __restrict__ sc,
                                                       const float* __restrict__ zp,
                                                       float* __restrict__ out) {
  __shared__ float xs[K_DIM];
  const int m = blockIdx.y;
  const int n = blockIdx.x * 256 + threadIdx.x;
  for (int i = threadIdx.x; i < K_DIM; i += 256) xs[i] = x[(size_t)m * K_DIM + i];
  __syncthreads();
  float acc = 0.f;
  const int* wrow = qw + (size_t)n * (K_DIM / 2);
  for (int g = 0; g < NGROUP; ++g) {
    float s = sc[n * NGROUP + g];
    float z = zp[n * NGROUP + g];
    float partial = 0.f;
    for (int p = 0; p < 64; ++p) {
      int q = wrow[g * 64 + p];
      partial += xs[g * 128 + 2 * p]     * ((float)(q & 15) - z);
      partial += xs[g * 128 + 2 * p + 1] * ((float)((q >> 4) & 15) - z);
    }
    acc = fmaf(partial, s, acc);
  }
  out[(size_t)m * N_DIM + n] = acc;
}

extern "C" void kernel_launch(void* const* d_in, const int* in_sizes, int n_in,
                              void* d_out, int out_size, void* d_ws, size_t ws_size,
                              hipStream_t stream) {
  const float* x  = (const float*)d_in[0];
  const int*   qw = (const int*)d_in[1];
  const float* sc = (const float*)d_in[2];
  const float* zp = (const float*)d_in[3];
  float* out = (float*)d_out;

  const size_t xb_bytes = (size_t)M_DIM * K_DIM * 2;
  const size_t wb_bytes = (size_t)N_DIM * K_DIM * 2;

  if (ws_size >= xb_bytes + wb_bytes) {
    unsigned short* xb = (unsigned short*)d_ws;
    unsigned short* wb = (unsigned short*)((char*)d_ws + xb_bytes);
    cvt_x_kernel<<<dim3((unsigned)((size_t)M_DIM * K_DIM / (256 * 8))), 256, 0, stream>>>(x, xb);
    dequant_kernel<<<dim3((unsigned)((size_t)N_DIM * (K_DIM / 2) / 4 / 256)), 256, 0, stream>>>(qw, sc, zp, wb);
    dim3 grid((M_DIM / BM) * (N_DIM / BN));  // 32*43 = 1376
    gemm_8phase_kernel<<<grid, dim3(512), 131072, stream>>>(xb, wb, out);
  } else {
    dim3 grid(N_DIM / 256, M_DIM);
    fallback_kernel<<<grid, 256, 0, stream>>>(x, qw, sc, zp, out);
  }
}

// Round 3
// 788.276 us; speedup vs baseline: 1.3271x; 1.0256x over previous
//
#include <hip/hip_runtime.h>
#include <hip/hip_bf16.h>
#include <stdint.h>

// Problem constants: B=4, S=2048, IN=4096, OUT=11008
#define M_DIM 8192   // B*S
#define N_DIM 11008  // OUT
#define K_DIM 4096   // IN
#define NGROUP 32    // K_DIM/128

#define BM 256
#define BN 256
#define BK 64
#define NT (K_DIM / BK)  // 64 K-tiles

typedef __attribute__((ext_vector_type(4))) float f32x4;
typedef __attribute__((ext_vector_type(8))) short short8;
typedef __attribute__((ext_vector_type(8))) __bf16 bf16x8;

static_assert(M_DIM % BM == 0 && N_DIM % BN == 0 && K_DIM % BK == 0, "tiling");

__device__ __forceinline__ unsigned short f2bf(float f) {
  union { float f; unsigned int u; } v; v.f = f;
  unsigned int r = v.u + 0x7FFFu + ((v.u >> 16) & 1u);  // RNE
  return (unsigned short)(r >> 16);
}

// ---------- prepass 1: x fp32 -> bf16 ----------
__global__ __launch_bounds__(256) void cvt_x_kernel(const float* __restrict__ x,
                                                    unsigned short* __restrict__ xb) {
  size_t i = ((size_t)blockIdx.x * 256 + threadIdx.x) * 8;
  float4 a = *(const float4*)(x + i);
  float4 b = *(const float4*)(x + i + 4);
  short8 o;
  o[0] = (short)f2bf(a.x); o[1] = (short)f2bf(a.y);
  o[2] = (short)f2bf(a.z); o[3] = (short)f2bf(a.w);
  o[4] = (short)f2bf(b.x); o[5] = (short)f2bf(b.y);
  o[6] = (short)f2bf(b.z); o[7] = (short)f2bf(b.w);
  *(short8*)(xb + i) = o;
}

// ---------- prepass 2: dequant packed int4 -> bf16 W[N][K] ----------
__global__ __launch_bounds__(256) void dequant_kernel(const int* __restrict__ qw,
                                                      const float* __restrict__ sc,
                                                      const float* __restrict__ zp,
                                                      unsigned short* __restrict__ W) {
  size_t chunk = (size_t)blockIdx.x * 256 + threadIdx.x;  // 4 packed int32 = 8 weights
  int row = (int)(chunk >> 9);
  int c4  = (int)(chunk & 511);
  int g   = c4 >> 4;
  float s = sc[row * NGROUP + g];
  float z = zp[row * NGROUP + g];
  int4 q = *(const int4*)(qw + (size_t)row * 2048 + c4 * 4);
  int qq[4] = {q.x, q.y, q.z, q.w};
  short8 o;
#pragma unroll
  for (int t = 0; t < 4; ++t) {
    o[2 * t]     = (short)f2bf(((float)(qq[t] & 15)        - z) * s);
    o[2 * t + 1] = (short)f2bf(((float)((qq[t] >> 4) & 15) - z) * s);
  }
  *(short8*)(W + (size_t)row * K_DIM + (size_t)c4 * 8) = o;
}

// ---------- 256x256 8-phase GEMM: C[M][N] = A[M][K] * B[N][K]^T (bf16 in, f32 out) ----------
__device__ __forceinline__ void gload_lds16(const void* g, void* l) {
  __builtin_amdgcn_global_load_lds((__attribute__((address_space(1))) void*)g,
                                   (__attribute__((address_space(3))) void*)l,
                                   16, 0, 0);
}

// Stage one k-half panel [256 rows][32 cols] bf16 = 16KB, 2 x global_load_lds per thread.
// LDS dest LINEAR; swizzle applied on GLOBAL source column (rule #21):
// physical 16B-block cblk holds logical cblk ^ ((row>>1)&3).
__device__ __forceinline__ void stage_half(unsigned short* panel,
                                           const unsigned short* gbase,
                                           int kt, int kh, int tid, int wave) {
  const int cl = (tid & 3) ^ ((tid >> 3) & 3);
  const int r0 = tid >> 2;
  const int colg = kt * 64 + kh * 32 + cl * 8;
#pragma unroll
  for (int i = 0; i < 2; ++i) {
    const unsigned short* src = gbase + (size_t)(i * 128 + r0) * K_DIM + colg;
    unsigned short* dst = panel + (size_t)(i * 512 + wave * 64) * 8;
    gload_lds16(src, dst);
  }
}

#define VMC(N) asm volatile("s_waitcnt vmcnt(" #N ")" ::: "memory")

// Phase reading BOTH av (per m-half) and bv (reused across m-halves of this k-half).
#define PHASE_RB(PA, PB, MH, STAGE_STMT, VM_STMT)                                   \
  {                                                                                 \
    bf16x8 av[4];                                                                   \
    _Pragma("unroll") for (int m_ = 0; m_ < 4; ++m_)                                \
      av[m_] = *(const bf16x8*)&(PA)[abase + ((MH)*4 + m_) * 512];                  \
    _Pragma("unroll") for (int n_ = 0; n_ < 4; ++n_)                                \
      bv[n_] = *(const bf16x8*)&(PB)[bbase + n_ * 512];                             \
    STAGE_STMT;                                                                     \
    __builtin_amdgcn_s_barrier();                                                   \
    __builtin_amdgcn_s_setprio(1);                                                  \
    _Pragma("unroll") for (int m_ = 0; m_ < 4; ++m_)                                \
      _Pragma("unroll") for (int n_ = 0; n_ < 4; ++n_)                              \
        acc[(MH)*4 + m_][n_] =                                                      \
            __builtin_amdgcn_mfma_f32_16x16x32_bf16(av[m_], bv[n_],                 \
                                                    acc[(MH)*4 + m_][n_], 0, 0, 0); \
    __builtin_amdgcn_s_setprio(0);                                                  \
    VM_STMT;                                                                        \
    __builtin_amdgcn_s_barrier();                                                   \
  }

// Phase reusing bv from the previous phase (same k-half), reads only av.
#define PHASE_NB(PA, MH, STAGE_STMT, VM_STMT)                                       \
  {                                                                                 \
    bf16x8 av[4];                                                                   \
    _Pragma("unroll") for (int m_ = 0; m_ < 4; ++m_)                                \
      av[m_] = *(const bf16x8*)&(PA)[abase + ((MH)*4 + m_) * 512];                  \
    STAGE_STMT;                                                                     \
    __builtin_amdgcn_s_barrier();                                                   \
    __builtin_amdgcn_s_setprio(1);                                                  \
    _Pragma("unroll") for (int m_ = 0; m_ < 4; ++m_)                                \
      _Pragma("unroll") for (int n_ = 0; n_ < 4; ++n_)                              \
        acc[(MH)*4 + m_][n_] =                                                      \
            __builtin_amdgcn_mfma_f32_16x16x32_bf16(av[m_], bv[n_],                 \
                                                    acc[(MH)*4 + m_][n_], 0, 0, 0); \
    __builtin_amdgcn_s_setprio(0);                                                  \
    VM_STMT;                                                                        \
    __builtin_amdgcn_s_barrier();                                                   \
  }

__global__ __launch_bounds__(512, 2) void gemm_8phase_kernel(const unsigned short* __restrict__ A,
                                                             const unsigned short* __restrict__ B,
                                                             float* __restrict__ C) {
  extern __shared__ unsigned short lds[];
  unsigned short* As = lds;            // [2 buf][2 kh][256*32]  = 64KB
  unsigned short* Bs = lds + 32768;    // same                   = 64KB

  const int tid  = threadIdx.x;
  const int wave = tid >> 6;
  const int lane = tid & 63;
  const int wm = wave >> 2;   // 0..1 -> 128-row slab
  const int wn = wave & 3;    // 0..3 -> 64-col slab
  const int fr = lane & 15;
  const int cp = (lane >> 4) ^ ((fr >> 1) & 3);  // swizzled physical 16B-block

  // XCD-chunked block swizzle (1376 = 8*172, bijective), then bm-major mapping
  const int wg  = blockIdx.x;
  const int swz = (wg & 7) * 172 + (wg >> 3);
  const int bm = swz / 43;
  const int bn = swz % 43;
  const size_t row0 = (size_t)bm * BM;
  const size_t col0 = (size_t)bn * BN;

  const unsigned short* Ab = A + row0 * K_DIM;
  const unsigned short* Bb = B + col0 * K_DIM;

  const int abase = (wm * 128 + fr) * 32 + cp * 8;
  const int bbase = (wn * 64 + fr) * 32 + cp * 8;

  f32x4 acc[8][4];
#pragma unroll
  for (int i = 0; i < 8; ++i)
#pragma unroll
    for (int j = 0; j < 4; ++j) acc[i][j] = (f32x4){0.f, 0.f, 0.f, 0.f};

  bf16x8 bv[4];  // hoisted B fragments, live across one k-half (2 phases)

  // ---- prologue: stage tile 0 fully ----
  stage_half(As + 0 * 8192, Ab, 0, 0, tid, wave);
  stage_half(Bs + 0 * 8192, Bb, 0, 0, tid, wave);
  stage_half(As + 1 * 8192, Ab, 0, 1, tid, wave);
  stage_half(Bs + 1 * 8192, Bb, 0, 1, tid, wave);
  VMC(4);                       // Ak0,Bk0 landed; Ak1,Bk1 may be in flight
  __builtin_amdgcn_s_barrier();

  // ---- main loop: 4 phases per K-tile, 1 half-tile prefetch per phase ----
  for (int T = 0; T < NT - 1; ++T) {
    const int buf = T & 1, nb = buf ^ 1;
    unsigned short* A0 = As + (buf * 2 + 0) * 8192;
    unsigned short* A1 = As + (buf * 2 + 1) * 8192;
    unsigned short* B0 = Bs + (buf * 2 + 0) * 8192;
    unsigned short* B1 = Bs + (buf * 2 + 1) * 8192;
    unsigned short* nA0 = As + (nb * 2 + 0) * 8192;
    unsigned short* nA1 = As + (nb * 2 + 1) * 8192;
    unsigned short* nB0 = Bs + (nb * 2 + 0) * 8192;
    unsigned short* nB1 = Bs + (nb * 2 + 1) * 8192;

    // ph1: (k0, mh0) reads av+bv, prefetch (T+1).Ak0
    PHASE_RB(A0, B0, 0, stage_half(nA0, Ab, T + 1, 0, tid, wave), );
    // ph2: (k0, mh1) reuses bv, prefetch (T+1).Bk0; drain T.Ak1,T.Bk1 (for ph3/ph4)
    PHASE_NB(A0, 1, stage_half(nB0, Bb, T + 1, 0, tid, wave), VMC(4));
    // ph3: (k1, mh0) reads av+bv, prefetch (T+1).Ak1
    PHASE_RB(A1, B1, 0, stage_half(nA1, Ab, T + 1, 1, tid, wave), );
    // ph4: (k1, mh1) reuses bv, prefetch (T+1).Bk1; drain (T+1).Ak0,Bk0 (for next ph1)
    PHASE_NB(A1, 1, stage_half(nB1, Bb, T + 1, 1, tid, wave), VMC(4));
  }
  // ---- last tile: no prefetch; drain before k1 phases ----
  {
    const int buf = (NT - 1) & 1;
    unsigned short* A0 = As + (buf * 2 + 0) * 8192;
    unsigned short* A1 = As + (buf * 2 + 1) * 8192;
    unsigned short* B0 = Bs + (buf * 2 + 0) * 8192;
    unsigned short* B1 = Bs + (buf * 2 + 1) * 8192;
    PHASE_RB(A0, B0, 0, , );
    PHASE_NB(A0, 1, , VMC(0));
    PHASE_RB(A1, B1, 0, , );
    PHASE_NB(A1, 1, , );
  }

  // ---- epilogue: C/D layout col = lane&15, row = (lane>>4)*4 + v ----
  const int orow = (lane >> 4) * 4;
#pragma unroll
  for (int mi = 0; mi < 8; ++mi) {
#pragma unroll
    for (int n = 0; n < 4; ++n) {
      const size_t r = row0 + wm * 128 + mi * 16 + orow;
      const size_t c = col0 + wn * 64 + n * 16 + fr;
#pragma unroll
      for (int v = 0; v < 4; ++v)
        C[(r + v) * N_DIM + c] = acc[mi][n][v];
    }
  }
}

// ---------- fallback (only if d_ws too small): naive fused ----------
__global__ __launch_bounds__(256) void fallback_kernel(const float* __restrict__ x,
                                                       const int* __restrict__ qw,
                                                       const float* __restrict__ sc,
                                                       const float* __restrict__ zp,
                                                       float* __restrict__ out) {
  __shared__ float xs[K_DIM];
  const int m = blockIdx.y;
  const int n = blockIdx.x * 256 + threadIdx.x;
  for (int i = threadIdx.x; i < K_DIM; i += 256) xs[i] = x[(size_t)m * K_DIM + i];
  __syncthreads();
  float acc = 0.f;
  const int* wrow = qw + (size_t)n * (K_DIM / 2);
  for (int g = 0; g < NGROUP; ++g) {
    float s = sc[n * NGROUP + g];
    float z = zp[n * NGROUP + g];
    float partial = 0.f;
    for (int p = 0; p < 64; ++p) {
      int q = wrow[g * 64 + p];
      partial += xs[g * 128 + 2 * p]     * ((float)(q & 15) - z);
      partial += xs[g * 128 + 2 * p + 1] * ((float)((q >> 4) & 15) - z);
    }
    acc = fmaf(partial, s, acc);
  }
  out[(size_t)m * N_DIM + n] = acc;
}

extern "C" void kernel_launch(void* const* d_in, const int* in_sizes, int n_in,
                              void* d_out, int out_size, void* d_ws, size_t ws_size,
                              hipStream_t stream) {
  const float* x  = (const float*)d_in[0];
  const int*   qw = (const int*)d_in[1];
  const float* sc = (const float*)d_in[2];
  const float* zp = (const float*)d_in[3];
  float* out = (float*)d_out;

  const size_t xb_bytes = (size_t)M_DIM * K_DIM * 2;
  const size_t wb_bytes = (size_t)N_DIM * K_DIM * 2;

  if (ws_size >= xb_bytes + wb_bytes) {
    unsigned short* xb = (unsigned short*)d_ws;
    unsigned short* wb = (unsigned short*)((char*)d_ws + xb_bytes);
    cvt_x_kernel<<<dim3((unsigned)((size_t)M_DIM * K_DIM / (256 * 8))), 256, 0, stream>>>(x, xb);
    dequant_kernel<<<dim3((unsigned)((size_t)N_DIM * (K_DIM / 2) / 4 / 256)), 256, 0, stream>>>(qw, sc, zp, wb);
    dim3 grid((M_DIM / BM) * (N_DIM / BN));  // 32*43 = 1376
    gemm_8phase_kernel<<<grid, dim3(512), 131072, stream>>>(xb, wb, out);
  } else {
    dim3 grid(N_DIM / 256, M_DIM);
    fallback_kernel<<<grid, 256, 0, stream>>>(x, qw, sc, zp, out);
  }
}